// Round 5
// baseline (703.255 us; speedup 1.0000x reference)
//
#include <hip/hip_runtime.h>

#define B_  16
#define L_  1024
#define E_  256
#define H_  8
#define DH_ 32
#define M_  (B_ * L_)           // 16384 rows
#define QKV_N 768
#define SCALE 0.17677669529663687f  // 1/sqrt(32)

typedef unsigned short u16;
typedef unsigned int   u32;

static __device__ __forceinline__ float bf2f(u16 u) {
    return __uint_as_float(((u32)u) << 16);
}
static __device__ __forceinline__ u16 f2bf(float f) {
    u32 u = __float_as_uint(f);
    u32 r = 0x7FFFu + ((u >> 16) & 1u);   // RNE
    return (u16)((u + r) >> 16);
}
static __device__ __forceinline__ u32 pack2(float a, float b) {
    return (u32)f2bf(a) | ((u32)f2bf(b) << 16);
}
static __device__ __forceinline__ void unpk(u32 v, float& a, float& b) {
    a = __uint_as_float(v << 16);
    b = __uint_as_float(v & 0xFFFF0000u);
}

// sum-reduce (s, q) across a 256-thread block; result valid in all threads
static __device__ __forceinline__ void blk_reduce2(float& s, float& q) {
    __shared__ float sm[8];
    #pragma unroll
    for (int off = 32; off > 0; off >>= 1) {
        s += __shfl_down(s, off, 64);
        q += __shfl_down(q, off, 64);
    }
    int lane = threadIdx.x & 63, w = threadIdx.x >> 6;
    if (lane == 0) { sm[w] = s; sm[4 + w] = q; }
    __syncthreads();
    s = sm[0] + sm[1] + sm[2] + sm[3];
    q = sm[4] + sm[5] + sm[6] + sm[7];
    __syncthreads();
}

// ---------------- kernel 1: embedding gather + layernorm -> bf16 ----------------
__global__ __launch_bounds__(256) void embed_ln_k(
    const int* __restrict__ seq,
    const float* __restrict__ emb_w,   // [L, E, 4] fp32
    const float* __restrict__ emb_b,   // [L, E] fp32
    u16* __restrict__ emb)             // [M, E] bf16
{
    int bl = blockIdx.x;               // b*L + l
    int l  = bl & (L_ - 1);
    int e  = threadIdx.x;
    int cls = seq[bl];
    float x = emb_w[((size_t)l * E_ + e) * 4 + cls] + emb_b[l * E_ + e];
    float s = x, q = x * x;
    blk_reduce2(s, q);
    float mean = s * (1.0f / E_);
    float var  = q * (1.0f / E_) - mean * mean;
    emb[(size_t)bl * E_ + e] = f2bf((x - mean) * rsqrtf(var + 1e-5f));
}

// ---------------- kernel 2: qkv = emb @ in_proj_w^T + b  (bf16 A, fp32 W, bf16 C)
// M=16384, N=768, K=256. 64x64 tile, BK=16, 256 threads, 4x4/thread.
__global__ __launch_bounds__(256) void gemm_qkv_k(
    const u16*  __restrict__ A,       // [M,256] bf16
    const float* __restrict__ W,      // [768,256] fp32
    const float* __restrict__ bias,   // [768] fp32
    u16* __restrict__ C)              // [M,768] bf16
{
    __shared__ float As[16][68];      // [k][m]
    __shared__ float Bs[16][68];      // [k][n]
    int tid = threadIdx.x;
    int m0 = blockIdx.y * 64, n0 = blockIdx.x * 64;
    int lr = tid >> 2, lc = (tid & 3) * 4;
    int tx = tid & 15, ty = tid >> 4;

    const u16*   Ap = A + (size_t)(m0 + lr) * 256 + lc;
    const float* Wp = W + (size_t)(n0 + lr) * 256 + lc;

    float acc[4][4] = {};
    for (int k0 = 0; k0 < 256; k0 += 16) {
        ushort4 a4 = *(const ushort4*)(Ap + k0);
        float4  b4 = *(const float4*)(Wp + k0);
        __syncthreads();
        As[lc + 0][lr] = bf2f(a4.x); As[lc + 1][lr] = bf2f(a4.y);
        As[lc + 2][lr] = bf2f(a4.z); As[lc + 3][lr] = bf2f(a4.w);
        Bs[lc + 0][lr] = b4.x; Bs[lc + 1][lr] = b4.y;
        Bs[lc + 2][lr] = b4.z; Bs[lc + 3][lr] = b4.w;
        __syncthreads();
        #pragma unroll
        for (int k = 0; k < 16; ++k) {
            float4 av = *(const float4*)(&As[k][ty * 4]);
            float4 bv = *(const float4*)(&Bs[k][tx * 4]);
            float a[4] = {av.x, av.y, av.z, av.w};
            float b[4] = {bv.x, bv.y, bv.z, bv.w};
            #pragma unroll
            for (int i = 0; i < 4; ++i)
                #pragma unroll
                for (int j = 0; j < 4; ++j)
                    acc[i][j] += a[i] * b[j];
        }
    }
    float bj[4];
    #pragma unroll
    for (int j = 0; j < 4; ++j) bj[j] = bias[n0 + tx * 4 + j];
    #pragma unroll
    for (int i = 0; i < 4; ++i) {
        ushort4 o = { f2bf(acc[i][0] + bj[0]), f2bf(acc[i][1] + bj[1]),
                      f2bf(acc[i][2] + bj[2]), f2bf(acc[i][3] + bj[3]) };
        *(ushort4*)(C + (size_t)(m0 + ty * 4 + i) * QKV_N + n0 + tx * 4) = o;
    }
}

// ---------------- kernel 3: flash-style attention, 1 thread = 1 q row -----------
__global__ __launch_bounds__(256) void attn_k(
    const u16* __restrict__ qkv,   // [M, 768] bf16
    u16* __restrict__ ctx)         // [M, 256] bf16
{
    __shared__ float Kt[64][32];
    __shared__ float Vt[64][32];
    int b = blockIdx.z, h = blockIdx.y, qc = blockIdx.x;
    int tid = threadIdx.x;
    int qrow = qc * 256 + tid;

    const u16* qp = qkv + (size_t)(b * L_ + qrow) * QKV_N + h * DH_;
    float q[32];
    #pragma unroll
    for (int d8 = 0; d8 < 4; ++d8) {
        uint4 t = *(const uint4*)(qp + d8 * 8);
        unpk(t.x, q[d8*8+0], q[d8*8+1]); unpk(t.y, q[d8*8+2], q[d8*8+3]);
        unpk(t.z, q[d8*8+4], q[d8*8+5]); unpk(t.w, q[d8*8+6], q[d8*8+7]);
    }
    #pragma unroll
    for (int d = 0; d < 32; ++d) q[d] *= SCALE;

    float O[32];
    #pragma unroll
    for (int d = 0; d < 32; ++d) O[d] = 0.0f;
    float mx = -1e30f, lsum = 0.0f;

    int j = tid >> 2, c = tid & 3;
    for (int kt = 0; kt < 16; ++kt) {
        const u16* kb = qkv + (size_t)(b * L_ + kt * 64 + j) * QKV_N + E_ + h * DH_;
        uint4 kv = *(const uint4*)(kb + c * 8);
        uint4 vv = *(const uint4*)(kb + E_ + c * 8);
        __syncthreads();
        float* kd = &Kt[j][c * 8];
        unpk(kv.x, kd[0], kd[1]); unpk(kv.y, kd[2], kd[3]);
        unpk(kv.z, kd[4], kd[5]); unpk(kv.w, kd[6], kd[7]);
        float* vd = &Vt[j][c * 8];
        unpk(vv.x, vd[0], vd[1]); unpk(vv.y, vd[2], vd[3]);
        unpk(vv.z, vd[4], vd[5]); unpk(vv.w, vd[6], vd[7]);
        __syncthreads();
        #pragma unroll 2
        for (int jj = 0; jj < 64; ++jj) {
            const float* kr = Kt[jj];
            float s0 = 0, s1 = 0, s2 = 0, s3 = 0;
            #pragma unroll
            for (int d = 0; d < 32; d += 4) {
                s0 += q[d + 0] * kr[d + 0];
                s1 += q[d + 1] * kr[d + 1];
                s2 += q[d + 2] * kr[d + 2];
                s3 += q[d + 3] * kr[d + 3];
            }
            float s = (s0 + s1) + (s2 + s3);
            float mnew = fmaxf(mx, s);
            float p = __expf(s - mnew);
            if (mnew > mx) {
                float alpha = __expf(mx - mnew);
                lsum *= alpha;
                #pragma unroll
                for (int d = 0; d < 32; ++d) O[d] *= alpha;
                mx = mnew;
            }
            lsum += p;
            const float* vr = Vt[jj];
            #pragma unroll
            for (int d = 0; d < 32; ++d) O[d] += p * vr[d];
        }
    }
    float inv = 1.0f / lsum;
    u16* op = ctx + (size_t)(b * L_ + qrow) * E_ + h * DH_;
    #pragma unroll
    for (int d8 = 0; d8 < 4; ++d8) {
        uint4 o;
        o.x = pack2(O[d8*8+0] * inv, O[d8*8+1] * inv);
        o.y = pack2(O[d8*8+2] * inv, O[d8*8+3] * inv);
        o.z = pack2(O[d8*8+4] * inv, O[d8*8+5] * inv);
        o.w = pack2(O[d8*8+6] * inv, O[d8*8+7] * inv);
        *(uint4*)(op + d8 * 8) = o;
    }
}

// ------- kernel 4: out = LN(ctx @ out_w^T + out_b + embedded), fused epilogue ----
// Block = 64 rows x full N=256. 256 threads; thread (tx,ty) owns rows ty*4..+3,
// cols {g*64 + tx*4 .. +3} for g=0..3. LN row-stats via 16-lane shfl segments.
// Output written as fp32 (the reference's output dtype).
__global__ __launch_bounds__(256) void proj_resid_ln_k(
    const u16*  __restrict__ ctx,     // [M,256] bf16
    const float* __restrict__ W,      // [256,256] fp32
    const float* __restrict__ bias,   // [256] fp32
    const u16*  __restrict__ emb,     // [M,256] bf16
    float* __restrict__ out)          // [M,256] fp32
{
    __shared__ float As[16][68];      // [k][m]
    __shared__ float Bs[16][260];     // [k][n]
    int tid = threadIdx.x;
    int m0 = blockIdx.x * 64;
    int tx = tid & 15, ty = tid >> 4;
    int lr = tid >> 2, lc = (tid & 3) * 4;

    const u16*   Ap = ctx + (size_t)(m0 + lr) * 256 + lc;
    const float* Wp = W + (size_t)tid * 256;

    float acc[4][16] = {};
    for (int k0 = 0; k0 < 256; k0 += 16) {
        ushort4 a4 = *(const ushort4*)(Ap + k0);
        float4 b0 = *(const float4*)(Wp + k0);
        float4 b1 = *(const float4*)(Wp + k0 + 4);
        float4 b2 = *(const float4*)(Wp + k0 + 8);
        float4 b3 = *(const float4*)(Wp + k0 + 12);
        __syncthreads();
        As[lc + 0][lr] = bf2f(a4.x); As[lc + 1][lr] = bf2f(a4.y);
        As[lc + 2][lr] = bf2f(a4.z); As[lc + 3][lr] = bf2f(a4.w);
        Bs[ 0][tid] = b0.x; Bs[ 1][tid] = b0.y; Bs[ 2][tid] = b0.z; Bs[ 3][tid] = b0.w;
        Bs[ 4][tid] = b1.x; Bs[ 5][tid] = b1.y; Bs[ 6][tid] = b1.z; Bs[ 7][tid] = b1.w;
        Bs[ 8][tid] = b2.x; Bs[ 9][tid] = b2.y; Bs[10][tid] = b2.z; Bs[11][tid] = b2.w;
        Bs[12][tid] = b3.x; Bs[13][tid] = b3.y; Bs[14][tid] = b3.z; Bs[15][tid] = b3.w;
        __syncthreads();
        #pragma unroll
        for (int k = 0; k < 16; ++k) {
            float4 av = *(const float4*)(&As[k][ty * 4]);
            float a[4] = {av.x, av.y, av.z, av.w};
            #pragma unroll
            for (int g = 0; g < 4; ++g) {
                float4 wv = *(const float4*)(&Bs[k][g * 64 + tx * 4]);
                float w[4] = {wv.x, wv.y, wv.z, wv.w};
                #pragma unroll
                for (int i = 0; i < 4; ++i)
                    #pragma unroll
                    for (int j = 0; j < 4; ++j)
                        acc[i][g * 4 + j] += a[i] * w[j];
            }
        }
    }

    float bcol[16];
    #pragma unroll
    for (int g = 0; g < 4; ++g)
        #pragma unroll
        for (int j = 0; j < 4; ++j) bcol[g * 4 + j] = bias[g * 64 + tx * 4 + j];

    #pragma unroll
    for (int i = 0; i < 4; ++i) {
        int row = m0 + ty * 4 + i;
        float x[16];
        #pragma unroll
        for (int g = 0; g < 4; ++g) {
            ushort4 e4 = *(const ushort4*)(emb + (size_t)row * 256 + g * 64 + tx * 4);
            x[g*4+0] = acc[i][g*4+0] + bcol[g*4+0] + bf2f(e4.x);
            x[g*4+1] = acc[i][g*4+1] + bcol[g*4+1] + bf2f(e4.y);
            x[g*4+2] = acc[i][g*4+2] + bcol[g*4+2] + bf2f(e4.z);
            x[g*4+3] = acc[i][g*4+3] + bcol[g*4+3] + bf2f(e4.w);
        }
        float s = 0, q = 0;
        #pragma unroll
        for (int j = 0; j < 16; ++j) { s += x[j]; q += x[j] * x[j]; }
        #pragma unroll
        for (int off = 8; off > 0; off >>= 1) {
            s += __shfl_down(s, off, 16);
            q += __shfl_down(q, off, 16);
        }
        s = __shfl(s, 0, 16);
        q = __shfl(q, 0, 16);
        float mean = s * (1.0f / 256.0f);
        float var  = q * (1.0f / 256.0f) - mean * mean;
        float rstd = rsqrtf(var + 1e-5f);
        #pragma unroll
        for (int g = 0; g < 4; ++g) {
            float4 o = { (x[g*4+0] - mean) * rstd, (x[g*4+1] - mean) * rstd,
                         (x[g*4+2] - mean) * rstd, (x[g*4+3] - mean) * rstd };
            *(float4*)(out + (size_t)row * 256 + g * 64 + tx * 4) = o;
        }
    }
}

extern "C" void kernel_launch(void* const* d_in, const int* in_sizes, int n_in,
                              void* d_out, int out_size, void* d_ws, size_t ws_size,
                              hipStream_t stream) {
    const int*   seq       = (const int*)d_in[0];
    const float* emb_w     = (const float*)d_in[1];
    const float* emb_b     = (const float*)d_in[2];
    const float* in_proj_w = (const float*)d_in[3];
    const float* in_proj_b = (const float*)d_in[4];
    const float* out_w     = (const float*)d_in[5];
    const float* out_b     = (const float*)d_in[6];
    float*       out       = (float*)d_out;

    u16* ws  = (u16*)d_ws;
    u16* emb = ws;                                  // [M,256]  8 MB
    u16* qkv = ws + (size_t)M_ * E_;                // [M,768] 24 MB
    u16* ctx = ws + (size_t)M_ * (E_ + QKV_N);      // [M,256]  8 MB  (total 40 MB)

    embed_ln_k<<<M_, 256, 0, stream>>>(seq, emb_w, emb_b, emb);
    gemm_qkv_k<<<dim3(QKV_N / 64, M_ / 64), 256, 0, stream>>>(emb, in_proj_w, in_proj_b, qkv);
    attn_k<<<dim3(L_ / 256, H_, B_), 256, 0, stream>>>(qkv, ctx);
    proj_resid_ln_k<<<M_ / 64, 256, 0, stream>>>(ctx, out_w, out_b, emb, out);
}

// Round 6
// 308.287 us; speedup vs baseline: 2.2812x; 2.2812x over previous
//
#include <hip/hip_runtime.h>

#define B_  16
#define L_  1024
#define E_  256
#define H_  8
#define DH_ 32
#define M_  (B_ * L_)           // 16384 rows
#define QKV_N 768
#define SCALE 0.17677669529663687f  // 1/sqrt(32)

typedef unsigned short u16;
typedef unsigned int   u32;
typedef short bf8_t __attribute__((ext_vector_type(8)));   // 8 bf16 (4 VGPRs)
typedef float f4_t  __attribute__((ext_vector_type(4)));   // MFMA acc

union F4U { uint4 u; bf8_t s; };

static __device__ __forceinline__ float bf2f(u16 u) {
    return __uint_as_float(((u32)u) << 16);
}
static __device__ __forceinline__ u16 f2bf(float f) {
    u32 u = __float_as_uint(f);
    u32 r = 0x7FFFu + ((u >> 16) & 1u);   // RNE
    return (u16)((u + r) >> 16);
}

// sum-reduce (s, q) across a 256-thread block; result valid in all threads
static __device__ __forceinline__ void blk_reduce2(float& s, float& q) {
    __shared__ float sm[8];
    #pragma unroll
    for (int off = 32; off > 0; off >>= 1) {
        s += __shfl_down(s, off, 64);
        q += __shfl_down(q, off, 64);
    }
    int lane = threadIdx.x & 63, w = threadIdx.x >> 6;
    if (lane == 0) { sm[w] = s; sm[4 + w] = q; }
    __syncthreads();
    s = sm[0] + sm[1] + sm[2] + sm[3];
    q = sm[4] + sm[5] + sm[6] + sm[7];
    __syncthreads();
}

// ---------------- kernel 1: embedding gather + layernorm -> bf16 ----------------
__global__ __launch_bounds__(256) void embed_ln_k(
    const int* __restrict__ seq,
    const float* __restrict__ emb_w,   // [L, E, 4] fp32
    const float* __restrict__ emb_b,   // [L, E] fp32
    u16* __restrict__ emb)             // [M, E] bf16
{
    int bl = blockIdx.x;               // b*L + l
    int l  = bl & (L_ - 1);
    int e  = threadIdx.x;
    int cls = seq[bl];
    float x = emb_w[((size_t)l * E_ + e) * 4 + cls] + emb_b[l * E_ + e];
    float s = x, q = x * x;
    blk_reduce2(s, q);
    float mean = s * (1.0f / E_);
    float var  = q * (1.0f / E_) - mean * mean;
    emb[(size_t)bl * E_ + e] = f2bf((x - mean) * rsqrtf(var + 1e-5f));
}

// ---------------- kernel 2: qkv = emb @ in_proj_w^T + b  (bf16 A, fp32 W, bf16 C)
// Q columns (n<256) are pre-scaled by 1/sqrt(DH) so attention skips the scale.
__global__ __launch_bounds__(256) void gemm_qkv_k(
    const u16*  __restrict__ A,       // [M,256] bf16
    const float* __restrict__ W,      // [768,256] fp32
    const float* __restrict__ bias,   // [768] fp32
    u16* __restrict__ C)              // [M,768] bf16
{
    __shared__ float As[16][68];      // [k][m]
    __shared__ float Bs[16][68];      // [k][n]
    int tid = threadIdx.x;
    int m0 = blockIdx.y * 64, n0 = blockIdx.x * 64;
    int lr = tid >> 2, lc = (tid & 3) * 4;
    int tx = tid & 15, ty = tid >> 4;

    const u16*   Ap = A + (size_t)(m0 + lr) * 256 + lc;
    const float* Wp = W + (size_t)(n0 + lr) * 256 + lc;

    float acc[4][4] = {};
    for (int k0 = 0; k0 < 256; k0 += 16) {
        ushort4 a4 = *(const ushort4*)(Ap + k0);
        float4  b4 = *(const float4*)(Wp + k0);
        __syncthreads();
        As[lc + 0][lr] = bf2f(a4.x); As[lc + 1][lr] = bf2f(a4.y);
        As[lc + 2][lr] = bf2f(a4.z); As[lc + 3][lr] = bf2f(a4.w);
        Bs[lc + 0][lr] = b4.x; Bs[lc + 1][lr] = b4.y;
        Bs[lc + 2][lr] = b4.z; Bs[lc + 3][lr] = b4.w;
        __syncthreads();
        #pragma unroll
        for (int k = 0; k < 16; ++k) {
            float4 av = *(const float4*)(&As[k][ty * 4]);
            float4 bv = *(const float4*)(&Bs[k][tx * 4]);
            float a[4] = {av.x, av.y, av.z, av.w};
            float b[4] = {bv.x, bv.y, bv.z, bv.w};
            #pragma unroll
            for (int i = 0; i < 4; ++i)
                #pragma unroll
                for (int j = 0; j < 4; ++j)
                    acc[i][j] += a[i] * b[j];
        }
    }
    float sc = (n0 < 256) ? SCALE : 1.0f;   // pre-scale Q
    float bj[4];
    #pragma unroll
    for (int j = 0; j < 4; ++j) bj[j] = bias[n0 + tx * 4 + j];
    #pragma unroll
    for (int i = 0; i < 4; ++i) {
        ushort4 o = { f2bf((acc[i][0] + bj[0]) * sc), f2bf((acc[i][1] + bj[1]) * sc),
                      f2bf((acc[i][2] + bj[2]) * sc), f2bf((acc[i][3] + bj[3]) * sc) };
        *(ushort4*)(C + (size_t)(m0 + ty * 4 + i) * QKV_N + n0 + tx * 4) = o;
    }
}

// ---------------- kernel 3a: transpose V -> vt[bh][d][L] -------------------------
__global__ __launch_bounds__(256) void transpose_v_k(
    const u16* __restrict__ qkv,      // [M,768]
    u16* __restrict__ vt)             // [128][32][1024]
{
    __shared__ u16 Vs[32 * 72];
    int tid = threadIdx.x;
    int bh = blockIdx.y, b = bh >> 3, h = bh & 7;
    int l0 = blockIdx.x * 64;
    int r = tid >> 2, dhb = (tid & 3) * 8;
    uint4 v = *(const uint4*)(qkv + ((size_t)b * L_ + l0 + r) * QKV_N + 512 + h * DH_ + dhb);
    u16 tmp[8]; *(uint4*)tmp = v;
    #pragma unroll
    for (int j = 0; j < 8; ++j)
        Vs[(dhb + j) * 72 + r] = tmp[j];
    __syncthreads();
    int d = tid >> 3, lb = (tid & 7) * 8;
    uint4 o = *(const uint4*)(Vs + d * 72 + lb);
    *(uint4*)(vt + ((size_t)bh * 32 + d) * L_ + l0 + lb) = o;
}

// ---------------- kernel 3b: MFMA flash attention -------------------------------
// Block: 256 thr = 4 waves; each wave owns a 16-row Q tile (64 rows/block).
// Per 64-K-row chunk: 4 score MFMAs -> online softmax (C-layout, quad-shuffles)
// -> P via LDS to A-layout -> 4 PV MFMAs (V from transposed vt, B-layout).
__global__ __launch_bounds__(256) void attn_mfma_k(
    const u16* __restrict__ qkv,   // [M,768] bf16 (Q pre-scaled)
    const u16* __restrict__ vt,    // [128][32][1024] bf16
    u16* __restrict__ ctx)         // [M,256] bf16
{
    __shared__ u16 Ks[64 * 40];        // [krow][dh], stride 40 el (80 B)
    __shared__ u16 Vs[32 * 72];        // [d][krow], stride 72 el (144 B)
    __shared__ u16 Ps[4][16 * 72];     // per-wave P [q][k], stride 72 el

    int tid = threadIdx.x;
    int w = tid >> 6, lane = tid & 63;
    int l15 = lane & 15, quad = lane >> 4;
    int bh = blockIdx.y, b = bh >> 3, h = bh & 7;
    int q0 = blockIdx.x * 64 + w * 16;
    size_t bL = (size_t)b * L_;

    // Q fragment: A[m=l15][k=quad*8+j] straight from global (once)
    F4U qf;
    qf.u = *(const uint4*)(qkv + (bL + q0 + l15) * QKV_N + h * DH_ + quad * 8);

    f4_t O0 = {0.f, 0.f, 0.f, 0.f}, O1 = {0.f, 0.f, 0.f, 0.f};
    float mrow[4] = {-1e30f, -1e30f, -1e30f, -1e30f};
    float lrow[4] = {0.f, 0.f, 0.f, 0.f};

    int srow = tid >> 2, sdh = (tid & 3) * 8;   // K staging map
    const u16* kgp = qkv + (bL + srow) * QKV_N + E_ + h * DH_ + sdh;
    int vd = tid >> 3, vl = (tid & 7) * 8;      // V staging map
    const u16* vgp = vt + ((size_t)bh * 32 + vd) * L_ + vl;
    u16* psw = Ps[w];

    for (int c = 0; c < 16; ++c) {
        uint4 kv = *(const uint4*)(kgp + (size_t)c * 64 * QKV_N);
        uint4 vv = *(const uint4*)(vgp + c * 64);
        __syncthreads();
        *(uint4*)(Ks + srow * 40 + sdh) = kv;
        *(uint4*)(Vs + vd * 72 + vl)    = vv;
        __syncthreads();

        // ---- scores: S[q=quad*4+r][krow = nt*16 + l15] ----
        float s[4][4];
        #pragma unroll
        for (int nt = 0; nt < 4; ++nt) {
            F4U kf; kf.u = *(const uint4*)(Ks + (nt * 16 + l15) * 40 + quad * 8);
            f4_t sc = {0.f, 0.f, 0.f, 0.f};
            sc = __builtin_amdgcn_mfma_f32_16x16x32_bf16(qf.s, kf.s, sc, 0, 0, 0);
            s[nt][0] = sc[0]; s[nt][1] = sc[1]; s[nt][2] = sc[2]; s[nt][3] = sc[3];
        }

        // ---- online softmax (row stats across the 16 lanes of each quad) ----
        float alpha[4];
        #pragma unroll
        for (int r = 0; r < 4; ++r) {
            float mx = fmaxf(fmaxf(s[0][r], s[1][r]), fmaxf(s[2][r], s[3][r]));
            mx = fmaxf(mx, __shfl_xor(mx, 1));
            mx = fmaxf(mx, __shfl_xor(mx, 2));
            mx = fmaxf(mx, __shfl_xor(mx, 4));
            mx = fmaxf(mx, __shfl_xor(mx, 8));
            float mnew = fmaxf(mrow[r], mx);
            alpha[r] = __expf(mrow[r] - mnew);
            mrow[r] = mnew;
        }
        #pragma unroll
        for (int r = 0; r < 4; ++r) {
            O0[r] *= alpha[r];
            O1[r] *= alpha[r];
            lrow[r] *= alpha[r];
        }
        #pragma unroll
        for (int r = 0; r < 4; ++r) {
            float psum = 0.f;
            #pragma unroll
            for (int nt = 0; nt < 4; ++nt) {
                float p = __expf(s[nt][r] - mrow[r]);
                psw[(quad * 4 + r) * 72 + nt * 16 + l15] = f2bf(p);
                psum += p;
            }
            psum += __shfl_xor(psum, 1);
            psum += __shfl_xor(psum, 2);
            psum += __shfl_xor(psum, 4);
            psum += __shfl_xor(psum, 8);
            lrow[r] += psum;
        }

        // ---- PV: O[q][d] += P[q][k] * V[k][d] ----
        #pragma unroll
        for (int kb = 0; kb < 2; ++kb) {
            F4U pf; pf.u = *(const uint4*)(psw + l15 * 72 + kb * 32 + quad * 8);
            F4U v0; v0.u = *(const uint4*)(Vs + l15 * 72 + kb * 32 + quad * 8);
            F4U v1; v1.u = *(const uint4*)(Vs + (16 + l15) * 72 + kb * 32 + quad * 8);
            O0 = __builtin_amdgcn_mfma_f32_16x16x32_bf16(pf.s, v0.s, O0, 0, 0, 0);
            O1 = __builtin_amdgcn_mfma_f32_16x16x32_bf16(pf.s, v1.s, O1, 0, 0, 0);
        }
    }

    #pragma unroll
    for (int r = 0; r < 4; ++r) {
        float inv = 1.0f / lrow[r];
        u16* op = ctx + (bL + q0 + quad * 4 + r) * E_ + h * DH_;
        op[l15]      = f2bf(O0[r] * inv);
        op[16 + l15] = f2bf(O1[r] * inv);
    }
}

// ------- kernel 4: out = LN(ctx @ out_w^T + out_b + embedded), fp32 out ----------
__global__ __launch_bounds__(256) void proj_resid_ln_k(
    const u16*  __restrict__ ctx,     // [M,256] bf16
    const float* __restrict__ W,      // [256,256] fp32
    const float* __restrict__ bias,   // [256] fp32
    const u16*  __restrict__ emb,     // [M,256] bf16
    float* __restrict__ out)          // [M,256] fp32
{
    __shared__ float As[16][68];      // [k][m]
    __shared__ float Bs[16][260];     // [k][n]
    int tid = threadIdx.x;
    int m0 = blockIdx.x * 64;
    int tx = tid & 15, ty = tid >> 4;
    int lr = tid >> 2, lc = (tid & 3) * 4;

    const u16*   Ap = ctx + (size_t)(m0 + lr) * 256 + lc;
    const float* Wp = W + (size_t)tid * 256;

    float acc[4][16] = {};
    for (int k0 = 0; k0 < 256; k0 += 16) {
        ushort4 a4 = *(const ushort4*)(Ap + k0);
        float4 b0 = *(const float4*)(Wp + k0);
        float4 b1 = *(const float4*)(Wp + k0 + 4);
        float4 b2 = *(const float4*)(Wp + k0 + 8);
        float4 b3 = *(const float4*)(Wp + k0 + 12);
        __syncthreads();
        As[lc + 0][lr] = bf2f(a4.x); As[lc + 1][lr] = bf2f(a4.y);
        As[lc + 2][lr] = bf2f(a4.z); As[lc + 3][lr] = bf2f(a4.w);
        Bs[ 0][tid] = b0.x; Bs[ 1][tid] = b0.y; Bs[ 2][tid] = b0.z; Bs[ 3][tid] = b0.w;
        Bs[ 4][tid] = b1.x; Bs[ 5][tid] = b1.y; Bs[ 6][tid] = b1.z; Bs[ 7][tid] = b1.w;
        Bs[ 8][tid] = b2.x; Bs[ 9][tid] = b2.y; Bs[10][tid] = b2.z; Bs[11][tid] = b2.w;
        Bs[12][tid] = b3.x; Bs[13][tid] = b3.y; Bs[14][tid] = b3.z; Bs[15][tid] = b3.w;
        __syncthreads();
        #pragma unroll
        for (int k = 0; k < 16; ++k) {
            float4 av = *(const float4*)(&As[k][ty * 4]);
            float a[4] = {av.x, av.y, av.z, av.w};
            #pragma unroll
            for (int g = 0; g < 4; ++g) {
                float4 wv = *(const float4*)(&Bs[k][g * 64 + tx * 4]);
                float wvv[4] = {wv.x, wv.y, wv.z, wv.w};
                #pragma unroll
                for (int i = 0; i < 4; ++i)
                    #pragma unroll
                    for (int j = 0; j < 4; ++j)
                        acc[i][g * 4 + j] += a[i] * wvv[j];
            }
        }
    }

    float bcol[16];
    #pragma unroll
    for (int g = 0; g < 4; ++g)
        #pragma unroll
        for (int j = 0; j < 4; ++j) bcol[g * 4 + j] = bias[g * 64 + tx * 4 + j];

    #pragma unroll
    for (int i = 0; i < 4; ++i) {
        int row = m0 + ty * 4 + i;
        float x[16];
        #pragma unroll
        for (int g = 0; g < 4; ++g) {
            ushort4 e4 = *(const ushort4*)(emb + (size_t)row * 256 + g * 64 + tx * 4);
            x[g*4+0] = acc[i][g*4+0] + bcol[g*4+0] + bf2f(e4.x);
            x[g*4+1] = acc[i][g*4+1] + bcol[g*4+1] + bf2f(e4.y);
            x[g*4+2] = acc[i][g*4+2] + bcol[g*4+2] + bf2f(e4.z);
            x[g*4+3] = acc[i][g*4+3] + bcol[g*4+3] + bf2f(e4.w);
        }
        float s = 0, q = 0;
        #pragma unroll
        for (int j = 0; j < 16; ++j) { s += x[j]; q += x[j] * x[j]; }
        #pragma unroll
        for (int off = 8; off > 0; off >>= 1) {
            s += __shfl_down(s, off, 16);
            q += __shfl_down(q, off, 16);
        }
        s = __shfl(s, 0, 16);
        q = __shfl(q, 0, 16);
        float mean = s * (1.0f / 256.0f);
        float var  = q * (1.0f / 256.0f) - mean * mean;
        float rstd = rsqrtf(var + 1e-5f);
        #pragma unroll
        for (int g = 0; g < 4; ++g) {
            float4 o = { (x[g*4+0] - mean) * rstd, (x[g*4+1] - mean) * rstd,
                         (x[g*4+2] - mean) * rstd, (x[g*4+3] - mean) * rstd };
            *(float4*)(out + (size_t)row * 256 + g * 64 + tx * 4) = o;
        }
    }
}

extern "C" void kernel_launch(void* const* d_in, const int* in_sizes, int n_in,
                              void* d_out, int out_size, void* d_ws, size_t ws_size,
                              hipStream_t stream) {
    const int*   seq       = (const int*)d_in[0];
    const float* emb_w     = (const float*)d_in[1];
    const float* emb_b     = (const float*)d_in[2];
    const float* in_proj_w = (const float*)d_in[3];
    const float* in_proj_b = (const float*)d_in[4];
    const float* out_w     = (const float*)d_in[5];
    const float* out_b     = (const float*)d_in[6];
    float*       out       = (float*)d_out;

    u16* ws  = (u16*)d_ws;
    u16* emb = ws;                                   // [M,256]   8 MB
    u16* qkv = ws + (size_t)M_ * 256;                // [M,768]  24 MB
    u16* ctx = ws + (size_t)M_ * (256 + 768);        // [M,256]   8 MB
    u16* vt  = ws + (size_t)M_ * (256 + 768 + 256);  // [128,32,1024] 8 MB (48 MB total)

    embed_ln_k<<<M_, 256, 0, stream>>>(seq, emb_w, emb_b, emb);
    gemm_qkv_k<<<dim3(QKV_N / 64, M_ / 64), 256, 0, stream>>>(emb, in_proj_w, in_proj_b, qkv);
    transpose_v_k<<<dim3(L_ / 64, B_ * H_), 256, 0, stream>>>(qkv, vt);
    attn_mfma_k<<<dim3(L_ / 64, B_ * H_), 256, 0, stream>>>(qkv, vt, ctx);
    proj_resid_ln_k<<<M_ / 64, 256, 0, stream>>>(ctx, out_w, out_b, emb, out);
}

// Round 7
// 269.852 us; speedup vs baseline: 2.6061x; 1.1424x over previous
//
#include <hip/hip_runtime.h>

#define B_  16
#define L_  1024
#define E_  256
#define H_  8
#define DH_ 32
#define M_  (B_ * L_)           // 16384 rows
#define SCALE 0.17677669529663687f  // 1/sqrt(32)

typedef unsigned short u16;
typedef unsigned int   u32;
typedef short bf8_t __attribute__((ext_vector_type(8)));   // 8 bf16 (4 VGPRs)
typedef float f4_t  __attribute__((ext_vector_type(4)));   // MFMA acc
union F4U { uint4 u; bf8_t s; };

static __device__ __forceinline__ float bf2f(u16 u) {
    return __uint_as_float(((u32)u) << 16);
}
static __device__ __forceinline__ u16 f2bf(float f) {
    u32 u = __float_as_uint(f);
    u32 r = 0x7FFFu + ((u >> 16) & 1u);   // RNE
    return (u16)((u + r) >> 16);
}
static __device__ __forceinline__ u32 pack2(float a, float b) {
    return (u32)f2bf(a) | ((u32)f2bf(b) << 16);
}

// sum-reduce (s, q) across a 256-thread block; result valid in all threads
static __device__ __forceinline__ void blk_reduce2(float& s, float& q) {
    __shared__ float sm[8];
    #pragma unroll
    for (int off = 32; off > 0; off >>= 1) {
        s += __shfl_down(s, off, 64);
        q += __shfl_down(q, off, 64);
    }
    int lane = threadIdx.x & 63, w = threadIdx.x >> 6;
    if (lane == 0) { sm[w] = s; sm[4 + w] = q; }
    __syncthreads();
    s = sm[0] + sm[1] + sm[2] + sm[3];
    q = sm[4] + sm[5] + sm[6] + sm[7];
    __syncthreads();
}

// ---- kernel 1: embedding gather + LN -> bf16; low blocks also convert W -> bf16
__global__ __launch_bounds__(256) void embed_conv_k(
    const int* __restrict__ seq,
    const float* __restrict__ emb_w,      // [L,E,4] fp32 (read as float4)
    const float* __restrict__ emb_b,      // [L,E]
    const float* __restrict__ in_proj_w,  // [768,256] fp32
    const float* __restrict__ out_w,      // [256,256] fp32
    u16* __restrict__ emb,                // [M,256] bf16
    u16* __restrict__ wcvt)               // [768*256 + 256*256] bf16 (wqkv|wout)
{
    int bl = blockIdx.x;
    int tid = threadIdx.x;
    if (bl < 1024) {                       // 1024*256 = 262144 weight elements
        int idx = bl * 256 + tid;
        float v = (idx < 196608) ? in_proj_w[idx] : out_w[idx - 196608];
        wcvt[idx] = f2bf(v);
    }
    int l = bl & (L_ - 1);
    int cls = seq[bl];
    float4 w4 = ((const float4*)emb_w)[l * 256 + tid];
    float x = (cls == 0) ? w4.x : (cls == 1) ? w4.y : (cls == 2) ? w4.z : w4.w;
    x += emb_b[l * 256 + tid];
    float s = x, q = x * x;
    blk_reduce2(s, q);
    float mean = s * (1.0f / E_);
    float var  = q * (1.0f / E_) - mean * mean;
    emb[(size_t)bl * E_ + tid] = f2bf((x - mean) * rsqrtf(var + 1e-5f));
}

// ---- kernel 2: QKV = emb @ Wqkv^T + b, MFMA, LDS-free (frags direct from global)
// Block 256thr/4 waves; wave w: rows m0+w*16, cols n0..n0+63. Outputs to
// head-major layouts: q_s/k_s [bh][l][32] (q pre-scaled), v_s [bh][l][32].
__global__ __launch_bounds__(256) void gemm_qkv_mfma_k(
    const u16* __restrict__ emb,      // [M,256] bf16
    const u16* __restrict__ wqkv,     // [768,256] bf16
    const float* __restrict__ bias,   // [768] fp32
    u16* __restrict__ q_s, u16* __restrict__ k_s, u16* __restrict__ v_s)
{
    int tid = threadIdx.x;
    int w = tid >> 6, lane = tid & 63, l15 = lane & 15, quad = lane >> 4;
    int n0 = blockIdx.x * 64, m0 = blockIdx.y * 64;

    const u16* Ap = emb  + (size_t)(m0 + w * 16 + l15) * 256 + quad * 8;
    const u16* Bp = wqkv + (size_t)(n0 + l15) * 256 + quad * 8;

    f4_t acc[4] = {{0,0,0,0},{0,0,0,0},{0,0,0,0},{0,0,0,0}};
    #pragma unroll
    for (int ks = 0; ks < 8; ++ks) {
        F4U a; a.u = *(const uint4*)(Ap + ks * 32);
        #pragma unroll
        for (int nc = 0; nc < 4; ++nc) {
            F4U b; b.u = *(const uint4*)(Bp + nc * 16 * 256 + ks * 32);
            acc[nc] = __builtin_amdgcn_mfma_f32_16x16x32_bf16(a.s, b.s, acc[nc], 0, 0, 0);
        }
    }
    #pragma unroll
    for (int nc = 0; nc < 4; ++nc) {
        int n = n0 + nc * 16 + l15;
        float bv = bias[n];
        float sc = (n < 256) ? SCALE : 1.0f;
        int sec = n >> 8, nl = n & 255, h = nl >> 5, d = nl & 31;
        u16* dst = (sec == 0) ? q_s : (sec == 1) ? k_s : v_s;
        #pragma unroll
        for (int r = 0; r < 4; ++r) {
            int m = m0 + w * 16 + quad * 4 + r;
            int b = m >> 10, l = m & 1023;
            dst[((size_t)(b * 8 + h) * 1024 + l) * 32 + d] = f2bf((acc[nc][r] + bv) * sc);
        }
    }
}

// ---- kernel 3: transpose V: v_s[bh][l][32] -> vt[bh][32][1024]
__global__ __launch_bounds__(256) void transpose_v_k(
    const u16* __restrict__ v_s, u16* __restrict__ vt)
{
    __shared__ u16 Vs[32 * 72];
    int tid = threadIdx.x;
    int bh = blockIdx.y, l0 = blockIdx.x * 64;
    int r = tid >> 2, db = (tid & 3) * 8;
    uint4 v = *(const uint4*)(v_s + ((size_t)bh * 1024 + l0 + r) * 32 + db);
    u16 tmp[8]; *(uint4*)tmp = v;
    #pragma unroll
    for (int j = 0; j < 8; ++j)
        Vs[(db + j) * 72 + r] = tmp[j];
    __syncthreads();
    int d = tid >> 3, lb = (tid & 7) * 8;
    uint4 o = *(const uint4*)(Vs + d * 72 + lb);
    *(uint4*)(vt + ((size_t)bh * 32 + d) * 1024 + l0 + lb) = o;
}

// ---- kernel 4: MFMA flash attention, fixed-max softmax, barrier-free K-loop.
// Scores computed transposed (A=K, B=Q -> C=S^T[key][q]) so P packs to LDS with
// ds_write_b64 and reads back as b128 A-frags. K/V read direct from global (L1).
__global__ __launch_bounds__(256) void attn2_k(
    const u16* __restrict__ q_s,   // [bh][l][32] (pre-scaled)
    const u16* __restrict__ k_s,   // [bh][l][32]
    const u16* __restrict__ vt,    // [bh][32][1024]
    u16* __restrict__ ctx)         // [bh][l][32]
{
    __shared__ u16 Ps[4][16 * 72];     // per-wave P [q][key], stride 72 el
    int tid = threadIdx.x;
    int w = tid >> 6, lane = tid & 63, l15 = lane & 15, quad = lane >> 4;
    int bh = blockIdx.y;
    int q0 = blockIdx.x * 64 + w * 16;

    const u16* kb = k_s + (size_t)bh * 1024 * 32;
    const u16* vb = vt  + (size_t)bh * 32 * 1024;
    u16* psw = Ps[w];

    F4U qf;   // B-frag: Q^T[d][q] -> lane holds Q[q=l15][d=quad*8+j]
    qf.u = *(const uint4*)(q_s + ((size_t)bh * 1024 + q0 + l15) * 32 + quad * 8);

    f4_t O0 = {0,0,0,0}, O1 = {0,0,0,0};
    float psum = 0.0f;

    for (int c = 0; c < 16; ++c) {
        int key0 = c * 64;
        // scores: S^T[key=nt*16+quad*4+r][q=l15]
        f4_t s[4];
        #pragma unroll
        for (int nt = 0; nt < 4; ++nt) {
            F4U kf; kf.u = *(const uint4*)(kb + (size_t)(key0 + nt * 16 + l15) * 32 + quad * 8);
            f4_t z = {0,0,0,0};
            s[nt] = __builtin_amdgcn_mfma_f32_16x16x32_bf16(kf.s, qf.s, z, 0, 0, 0);
        }
        // fixed-max softmax: p = exp(s); per-lane psum (q = l15 fixed per lane)
        #pragma unroll
        for (int nt = 0; nt < 4; ++nt) {
            float p0 = __expf(s[nt][0]), p1 = __expf(s[nt][1]);
            float p2 = __expf(s[nt][2]), p3 = __expf(s[nt][3]);
            psum += (p0 + p1) + (p2 + p3);
            uint2 pk = { pack2(p0, p1), pack2(p2, p3) };
            *(uint2*)(psw + l15 * 72 + nt * 16 + quad * 4) = pk;   // ds_write_b64
        }
        // PV: O[q][d] += P[q][key] * V[key][d]  (B-frag = vt rows, k-contiguous)
        #pragma unroll
        for (int k2 = 0; k2 < 2; ++k2) {
            F4U pf; pf.u = *(const uint4*)(psw + l15 * 72 + k2 * 32 + quad * 8);
            F4U v0; v0.u = *(const uint4*)(vb + (size_t)l15 * 1024 + key0 + k2 * 32 + quad * 8);
            F4U v1; v1.u = *(const uint4*)(vb + (size_t)(16 + l15) * 1024 + key0 + k2 * 32 + quad * 8);
            O0 = __builtin_amdgcn_mfma_f32_16x16x32_bf16(pf.s, v0.s, O0, 0, 0, 0);
            O1 = __builtin_amdgcn_mfma_f32_16x16x32_bf16(pf.s, v1.s, O1, 0, 0, 0);
        }
    }
    // lsum: reduce per-lane psum across quads (q = l15), then fetch per output row
    psum += __shfl_xor(psum, 16);
    psum += __shfl_xor(psum, 32);
    #pragma unroll
    for (int r = 0; r < 4; ++r) {
        float inv = 1.0f / __shfl(psum, quad * 4 + r, 64);
        u16* op = ctx + ((size_t)bh * 1024 + q0 + quad * 4 + r) * 32;
        op[l15]      = f2bf(O0[r] * inv);
        op[16 + l15] = f2bf(O1[r] * inv);
    }
}

// ---- kernel 5: proj = ctx @ Wout^T  (MFMA, LDS-free; bias added in LN kernel)
__global__ __launch_bounds__(256) void proj_gemm_k(
    const u16* __restrict__ ctx,      // [bh][l][32] bf16
    const u16* __restrict__ wout,     // [256,256] bf16
    u16* __restrict__ proj)           // [M,256] bf16
{
    int tid = threadIdx.x;
    int w = tid >> 6, lane = tid & 63, l15 = lane & 15, quad = lane >> 4;
    int n0 = blockIdx.x * 64, m0 = blockIdx.y * 64;
    int b = m0 >> 10, lbase = (m0 & 1023) + w * 16 + l15;

    const u16* Bp = wout + (size_t)(n0 + l15) * 256 + quad * 8;

    f4_t acc[4] = {{0,0,0,0},{0,0,0,0},{0,0,0,0},{0,0,0,0}};
    #pragma unroll
    for (int ks = 0; ks < 8; ++ks) {   // k = ks*32 + quad*8+j -> head ks, d
        F4U a; a.u = *(const uint4*)(ctx + ((size_t)(b * 8 + ks) * 1024 + lbase) * 32 + quad * 8);
        #pragma unroll
        for (int nc = 0; nc < 4; ++nc) {
            F4U bf; bf.u = *(const uint4*)(Bp + nc * 16 * 256 + ks * 32);
            acc[nc] = __builtin_amdgcn_mfma_f32_16x16x32_bf16(a.s, bf.s, acc[nc], 0, 0, 0);
        }
    }
    #pragma unroll
    for (int nc = 0; nc < 4; ++nc) {
        int n = n0 + nc * 16 + l15;
        #pragma unroll
        for (int r = 0; r < 4; ++r) {
            int m = m0 + w * 16 + quad * 4 + r;
            proj[(size_t)m * 256 + n] = f2bf(acc[nc][r]);
        }
    }
}

// ---- kernel 6: out = LN(proj + out_b + emb) -> fp32
__global__ __launch_bounds__(256) void resid_ln_k(
    const u16* __restrict__ proj,
    const u16* __restrict__ emb,
    const float* __restrict__ out_b,
    float* __restrict__ out)
{
    int bl = blockIdx.x, e = threadIdx.x;
    float x = bf2f(proj[(size_t)bl * 256 + e]) + bf2f(emb[(size_t)bl * 256 + e]) + out_b[e];
    float s = x, q = x * x;
    blk_reduce2(s, q);
    float mean = s * (1.0f / 256.0f);
    float var  = q * (1.0f / 256.0f) - mean * mean;
    out[(size_t)bl * 256 + e] = (x - mean) * rsqrtf(var + 1e-5f);
}

extern "C" void kernel_launch(void* const* d_in, const int* in_sizes, int n_in,
                              void* d_out, int out_size, void* d_ws, size_t ws_size,
                              hipStream_t stream) {
    const int*   seq       = (const int*)d_in[0];
    const float* emb_w     = (const float*)d_in[1];
    const float* emb_b     = (const float*)d_in[2];
    const float* in_proj_w = (const float*)d_in[3];
    const float* in_proj_b = (const float*)d_in[4];
    const float* out_w     = (const float*)d_in[5];
    const float* out_b     = (const float*)d_in[6];
    float*       out       = (float*)d_out;

    const size_t P = (size_t)M_ * 256;
    u16* ws   = (u16*)d_ws;
    u16* emb  = ws;                 //  8 MB
    u16* q_s  = ws + P;             //  8 MB  [bh][l][32]  (reused as proj)
    u16* k_s  = ws + 2 * P;         //  8 MB  [bh][l][32]
    u16* v_s  = ws + 3 * P;         //  8 MB  [bh][l][32]  (reused as ctx)
    u16* vt   = ws + 4 * P;         //  8 MB  [bh][32][1024]
    u16* wqkv = ws + 5 * P;         //  384 KB [768,256] bf16
    u16* wout = wqkv + 768 * 256;   //  128 KB [256,256] bf16
    u16* ctx  = v_s;                // v_s dead after transpose
    u16* proj = q_s;                // q_s dead after attn

    embed_conv_k<<<M_, 256, 0, stream>>>(seq, emb_w, emb_b, in_proj_w, out_w, emb, wqkv);
    gemm_qkv_mfma_k<<<dim3(12, 256), 256, 0, stream>>>(emb, wqkv, in_proj_b, q_s, k_s, v_s);
    transpose_v_k<<<dim3(16, 128), 256, 0, stream>>>(v_s, vt);
    attn2_k<<<dim3(16, 128), 256, 0, stream>>>(q_s, k_s, vt, ctx);
    proj_gemm_k<<<dim3(4, 256), 256, 0, stream>>>(ctx, wout, proj);
    resid_ln_k<<<M_, 256, 0, stream>>>(proj, emb, out_b, out);
}

// Round 8
// 249.794 us; speedup vs baseline: 2.8153x; 1.0803x over previous
//
#include <hip/hip_runtime.h>

#define B_  16
#define L_  1024
#define E_  256
#define H_  8
#define DH_ 32
#define M_  (B_ * L_)                 // 16384 rows
#define SCALE_L2E 0.25501817656f      // (1/sqrt(32)) * log2(e)

typedef unsigned short u16;
typedef unsigned int   u32;
typedef short bf8_t __attribute__((ext_vector_type(8)));   // 8 bf16 (4 VGPRs)
typedef float f4_t  __attribute__((ext_vector_type(4)));   // MFMA acc
union F4U { uint4 u; bf8_t s; };

static __device__ __forceinline__ float bf2f(u16 u) {
    return __uint_as_float(((u32)u) << 16);
}
static __device__ __forceinline__ u16 f2bf(float f) {
    u32 u = __float_as_uint(f);
    u32 r = 0x7FFFu + ((u >> 16) & 1u);   // RNE
    return (u16)((u + r) >> 16);
}
static __device__ __forceinline__ u32 pack2(float a, float b) {
    return (u32)f2bf(a) | ((u32)f2bf(b) << 16);
}

// ---- kernel 1: embedding gather + LN (wave-per-row); low blocks convert W->bf16
__global__ __launch_bounds__(256) void embed_conv_k(
    const int* __restrict__ seq,
    const float* __restrict__ emb_w,      // [L,E,4] fp32 (read as float4)
    const float* __restrict__ emb_b,      // [L,E]
    const float* __restrict__ in_proj_w,  // [768,256] fp32
    const float* __restrict__ out_w,      // [256,256] fp32
    u16* __restrict__ emb,                // [M,256] bf16
    u16* __restrict__ wcvt)               // [768*256 + 256*256] bf16 (wqkv|wout)
{
    int blk = blockIdx.x, tid = threadIdx.x;
    if (blk < 1024) {                      // 262144 weight elements
        int idx = blk * 256 + tid;
        float v = (idx < 196608) ? in_proj_w[idx] : out_w[idx - 196608];
        wcvt[idx] = f2bf(v);
    }
    int w = tid >> 6, lane = tid & 63;
    int bl = blk * 4 + w;                  // row in [0, M)
    int l = bl & (L_ - 1);
    int cls = seq[bl];
    const float4* wrow = (const float4*)emb_w + (size_t)l * 256;
    float4 bb = *(const float4*)(emb_b + (size_t)l * 256 + lane * 4);
    float bv[4] = {bb.x, bb.y, bb.z, bb.w};
    float x[4], s = 0.f, q = 0.f;
    #pragma unroll
    for (int j = 0; j < 4; ++j) {
        float4 w4 = wrow[lane * 4 + j];
        float t = ((cls == 0) ? w4.x : (cls == 1) ? w4.y : (cls == 2) ? w4.z : w4.w) + bv[j];
        x[j] = t; s += t; q += t * t;
    }
    #pragma unroll
    for (int off = 1; off < 64; off <<= 1) {
        s += __shfl_xor(s, off);
        q += __shfl_xor(q, off);
    }
    float mean = s * (1.0f / 256.0f);
    float var  = q * (1.0f / 256.0f) - mean * mean;
    float rstd = rsqrtf(var + 1e-5f);
    ushort4 o = { f2bf((x[0] - mean) * rstd), f2bf((x[1] - mean) * rstd),
                  f2bf((x[2] - mean) * rstd), f2bf((x[3] - mean) * rstd) };
    *(ushort4*)(emb + (size_t)bl * 256 + lane * 4) = o;
}

// ---- kernel 2: QKV = emb @ Wqkv^T + b (MFMA, LDS-free). Q pre-scaled by
// SCALE*log2(e); V written directly transposed into vt[bh][d][l] (ushort4).
__global__ __launch_bounds__(256) void gemm_qkv_mfma_k(
    const u16* __restrict__ emb,      // [M,256] bf16
    const u16* __restrict__ wqkv,     // [768,256] bf16
    const float* __restrict__ bias,   // [768] fp32
    u16* __restrict__ q_s, u16* __restrict__ k_s, u16* __restrict__ vt)
{
    int tid = threadIdx.x;
    int w = tid >> 6, lane = tid & 63, l15 = lane & 15, quad = lane >> 4;
    int n0 = blockIdx.x * 64, m0 = blockIdx.y * 64;

    const u16* Ap = emb  + (size_t)(m0 + w * 16 + l15) * 256 + quad * 8;
    const u16* Bp = wqkv + (size_t)(n0 + l15) * 256 + quad * 8;

    f4_t acc[4] = {{0,0,0,0},{0,0,0,0},{0,0,0,0},{0,0,0,0}};
    #pragma unroll
    for (int ks = 0; ks < 8; ++ks) {
        F4U a; a.u = *(const uint4*)(Ap + ks * 32);
        #pragma unroll
        for (int nc = 0; nc < 4; ++nc) {
            F4U b; b.u = *(const uint4*)(Bp + nc * 16 * 256 + ks * 32);
            acc[nc] = __builtin_amdgcn_mfma_f32_16x16x32_bf16(a.s, b.s, acc[nc], 0, 0, 0);
        }
    }
    int b = m0 >> 10;                       // batch (block never straddles)
    int lq = (m0 & 1023) + w * 16 + quad * 4;  // base l for this lane's 4 rows
    #pragma unroll
    for (int nc = 0; nc < 4; ++nc) {
        int n = n0 + nc * 16 + l15;
        float bv = bias[n];
        int nl = n & 255, h = nl >> 5, d = nl & 31;
        if (n < 512) {                      // Q or K: [bh][l][32]
            float sc = (n < 256) ? SCALE_L2E : 1.0f;
            u16* dst = (n < 256) ? q_s : k_s;
            #pragma unroll
            for (int r = 0; r < 4; ++r)
                dst[((size_t)(b * 8 + h) * 1024 + lq + r) * 32 + d] = f2bf((acc[nc][r] + bv) * sc);
        } else {                            // V transposed: vt[bh][d][l]
            ushort4 o = { f2bf(acc[nc][0] + bv), f2bf(acc[nc][1] + bv),
                          f2bf(acc[nc][2] + bv), f2bf(acc[nc][3] + bv) };
            *(ushort4*)(vt + ((size_t)(b * 8 + h) * 32 + d) * 1024 + lq) = o;
        }
    }
}

// ---- kernel 3: MFMA flash attention, fixed-max softmax, barrier-free,
// 2-chunk ping-pong register prefetch (vmcnt never drains to 0).
__global__ __launch_bounds__(256) void attn2_k(
    const u16* __restrict__ q_s,   // [bh][l][32] (pre-scaled by SCALE*log2e)
    const u16* __restrict__ k_s,   // [bh][l][32]
    const u16* __restrict__ vt,    // [bh][32][1024]
    u16* __restrict__ ctx)         // [bh][l][32]
{
    __shared__ u16 Ps[4][16 * 72];     // per-wave P [q][key], stride 72 el
    int tid = threadIdx.x;
    int w = tid >> 6, lane = tid & 63, l15 = lane & 15, quad = lane >> 4;
    int bh = blockIdx.y;
    int q0 = blockIdx.x * 64 + w * 16;

    const u16* kb = k_s + (size_t)bh * 1024 * 32;
    const u16* vb = vt  + (size_t)bh * 32 * 1024;
    u16* psw = Ps[w];

    F4U qf;   // B-frag: lane holds Q[q=l15][d=quad*8+j]
    qf.u = *(const uint4*)(q_s + ((size_t)bh * 1024 + q0 + l15) * 32 + quad * 8);

    f4_t O0 = {0,0,0,0}, O1 = {0,0,0,0};
    float psum = 0.0f;

    F4U kA[4], vA[4], kB[4], vB[4];

    auto LD = [&](F4U* k, F4U* v, int key0) {
        #pragma unroll
        for (int nt = 0; nt < 4; ++nt)
            k[nt].u = *(const uint4*)(kb + (size_t)(key0 + nt * 16 + l15) * 32 + quad * 8);
        #pragma unroll
        for (int k2 = 0; k2 < 2; ++k2) {
            v[k2 * 2 + 0].u = *(const uint4*)(vb + (size_t)l15 * 1024 + key0 + k2 * 32 + quad * 8);
            v[k2 * 2 + 1].u = *(const uint4*)(vb + (size_t)(16 + l15) * 1024 + key0 + k2 * 32 + quad * 8);
        }
    };
    auto STEP = [&](F4U* k, F4U* v) {
        f4_t s[4];
        #pragma unroll
        for (int nt = 0; nt < 4; ++nt) {
            f4_t z = {0,0,0,0};
            s[nt] = __builtin_amdgcn_mfma_f32_16x16x32_bf16(k[nt].s, qf.s, z, 0, 0, 0);
        }
        #pragma unroll
        for (int nt = 0; nt < 4; ++nt) {
            float p0 = exp2f(s[nt][0]), p1 = exp2f(s[nt][1]);
            float p2 = exp2f(s[nt][2]), p3 = exp2f(s[nt][3]);
            psum += (p0 + p1) + (p2 + p3);
            uint2 pk = { pack2(p0, p1), pack2(p2, p3) };
            *(uint2*)(psw + l15 * 72 + nt * 16 + quad * 4) = pk;
        }
        #pragma unroll
        for (int k2 = 0; k2 < 2; ++k2) {
            F4U pf; pf.u = *(const uint4*)(psw + l15 * 72 + k2 * 32 + quad * 8);
            O0 = __builtin_amdgcn_mfma_f32_16x16x32_bf16(pf.s, v[k2 * 2 + 0].s, O0, 0, 0, 0);
            O1 = __builtin_amdgcn_mfma_f32_16x16x32_bf16(pf.s, v[k2 * 2 + 1].s, O1, 0, 0, 0);
        }
    };

    LD(kA, vA, 0);
    for (int c = 0; c < 16; c += 2) {
        LD(kB, vB, (c + 1) * 64);
        STEP(kA, vA);
        if (c + 2 < 16) LD(kA, vA, (c + 2) * 64);
        STEP(kB, vB);
    }

    psum += __shfl_xor(psum, 16);
    psum += __shfl_xor(psum, 32);
    #pragma unroll
    for (int r = 0; r < 4; ++r) {
        float inv = 1.0f / __shfl(psum, quad * 4 + r, 64);
        u16* op = ctx + ((size_t)bh * 1024 + q0 + quad * 4 + r) * 32;
        op[l15]      = f2bf(O0[r] * inv);
        op[16 + l15] = f2bf(O1[r] * inv);
    }
}

// ---- kernel 4: out = LN(ctx @ Wout^T + out_b + emb) -> fp32, fully fused.
// Block = 64 rows x all 256 cols; wave w owns 16 rows; LN stats via shfl_xor
// over the 16-lane groups (C-layout cols nc*16+l15 span all 256).
__global__ __launch_bounds__(256) void proj_ln_k(
    const u16* __restrict__ ctx,      // [bh][l][32] bf16
    const u16* __restrict__ wout,     // [256,256] bf16
    const float* __restrict__ out_b,  // [256]
    const u16* __restrict__ emb,      // [M,256] bf16
    float* __restrict__ out)          // [M,256] fp32
{
    int tid = threadIdx.x;
    int w = tid >> 6, lane = tid & 63, l15 = lane & 15, quad = lane >> 4;
    int m0 = blockIdx.x * 64;
    int b = m0 >> 10, lbase = (m0 & 1023) + w * 16 + l15;

    const u16* Bp = wout + (size_t)l15 * 256 + quad * 8;

    f4_t acc[16];
    #pragma unroll
    for (int nc = 0; nc < 16; ++nc) acc[nc] = (f4_t){0,0,0,0};

    #pragma unroll
    for (int ks = 0; ks < 8; ++ks) {      // k = ks*32 + quad*8+j (head ks)
        F4U a; a.u = *(const uint4*)(ctx + ((size_t)(b * 8 + ks) * 1024 + lbase) * 32 + quad * 8);
        #pragma unroll
        for (int nc = 0; nc < 16; ++nc) {
            F4U bf; bf.u = *(const uint4*)(Bp + (size_t)nc * 16 * 256 + ks * 32);
            acc[nc] = __builtin_amdgcn_mfma_f32_16x16x32_bf16(a.s, bf.s, acc[nc], 0, 0, 0);
        }
    }

    float bcol[16];
    #pragma unroll
    for (int nc = 0; nc < 16; ++nc) bcol[nc] = out_b[nc * 16 + l15];

    #pragma unroll
    for (int r = 0; r < 4; ++r) {
        int row = m0 + w * 16 + quad * 4 + r;
        float x[16], s = 0.f, q = 0.f;
        #pragma unroll
        for (int nc = 0; nc < 16; ++nc) {
            float t = acc[nc][r] + bcol[nc] + bf2f(emb[(size_t)row * 256 + nc * 16 + l15]);
            x[nc] = t; s += t; q += t * t;
        }
        #pragma unroll
        for (int off = 1; off < 16; off <<= 1) {
            s += __shfl_xor(s, off);
            q += __shfl_xor(q, off);
        }
        float mean = s * (1.0f / 256.0f);
        float var  = q * (1.0f / 256.0f) - mean * mean;
        float rstd = rsqrtf(var + 1e-5f);
        #pragma unroll
        for (int nc = 0; nc < 16; ++nc)
            out[(size_t)row * 256 + nc * 16 + l15] = (x[nc] - mean) * rstd;
    }
}

extern "C" void kernel_launch(void* const* d_in, const int* in_sizes, int n_in,
                              void* d_out, int out_size, void* d_ws, size_t ws_size,
                              hipStream_t stream) {
    const int*   seq       = (const int*)d_in[0];
    const float* emb_w     = (const float*)d_in[1];
    const float* emb_b     = (const float*)d_in[2];
    const float* in_proj_w = (const float*)d_in[3];
    const float* in_proj_b = (const float*)d_in[4];
    const float* out_w     = (const float*)d_in[5];
    const float* out_b     = (const float*)d_in[6];
    float*       out       = (float*)d_out;

    const size_t P = (size_t)M_ * 256;
    u16* ws   = (u16*)d_ws;
    u16* emb  = ws;                 //  8 MB [M,256]
    u16* q_s  = ws + P;             //  8 MB [bh][l][32]
    u16* k_s  = ws + 2 * P;         //  8 MB [bh][l][32]
    u16* vt   = ws + 3 * P;         //  8 MB [bh][32][1024]
    u16* ctx  = ws + 4 * P;         //  8 MB [bh][l][32]
    u16* wqkv = ws + 5 * P;         //  384 KB [768,256] bf16
    u16* wout = wqkv + 768 * 256;   //  128 KB [256,256] bf16

    embed_conv_k<<<M_ / 4, 256, 0, stream>>>(seq, emb_w, emb_b, in_proj_w, out_w, emb, wqkv);
    gemm_qkv_mfma_k<<<dim3(12, 256), 256, 0, stream>>>(emb, wqkv, in_proj_b, q_s, k_s, vt);
    attn2_k<<<dim3(16, 128), 256, 0, stream>>>(q_s, k_s, vt, ctx);
    proj_ln_k<<<M_ / 64, 256, 0, stream>>>(ctx, wout, out_b, emb, out);
}